// Round 1
// baseline (1107.504 us; speedup 1.0000x reference)
//
#include <hip/hip_runtime.h>
#include <math.h>

#define ALPHA 0.2f
#define BN_EPS 1e-5f

// LDS layout (floats):
//   xh   [2][5][5][25]  = 1250   @0      (reused as p2f[384] in phase 10+)
//   cst  inv1/sh1/inv2/sh2 [4][32] = 128 @1250
//   h1   [2][32][25]    = 1600   @1378   (reused as h2 [2][32][13]=832)
//   aT   [2][32][33]    = 2112   @2978   (softmax rows padded to 33: stride-32
//                                         would put all 64 lanes on one bank)
//   out1 [2][32][25]    = 1600   @5090
//   p1   [2][32][13]    = 832    @6690   (reused as o2, stride 13 to dodge
//                                         gcd(12,32)=4 bank aliasing)
// total 7522 floats = 30.1 KB -> 5 blocks/CU, 20 waves/CU
#define LDS_TOTAL 7522

__global__ __launch_bounds__(256) void gcn_kernel(
    const float* __restrict__ x,
    const float* __restrict__ w1, const float* __restrict__ b1,
    const float* __restrict__ g1, const float* __restrict__ be1,
    const float* __restrict__ mu1, const float* __restrict__ va1,
    const float* __restrict__ w2, const float* __restrict__ b2,
    const float* __restrict__ g2, const float* __restrict__ be2,
    const float* __restrict__ mu2, const float* __restrict__ va2,
    const float* __restrict__ lw, const float* __restrict__ lb,
    float* __restrict__ out)
{
    __shared__ float lds[LDS_TOTAL];
    float* xh   = lds;          // 1250
    float* cst  = lds + 1250;   // 128
    float* h1   = lds + 1378;   // 1600 (h2 alias)
    float* aT   = lds + 2978;   // 2112
    float* out1 = lds + 5090;   // 1600
    float* p1   = lds + 6690;   // 832 (o2 alias)

    const int tid = threadIdx.x;
    const int b   = blockIdx.x;
    const float* xg = x + (size_t)b * 1250;

    // ---- phase 0: load input, precompute BN constants ----
    for (int i = tid; i < 1250; i += 256) {
        int c = i / 250; int r = i - c * 250;
        int h = r / 50;  int w50 = r - h * 50;
        int half = (w50 >= 25) ? 1 : 0;
        int w = w50 - half * 25;
        xh[((half * 5 + c) * 5 + h) * 25 + w] = xg[i];
    }
    if (tid < 64) {
        int oc = tid & 31;
        if (tid < 32) {
            float inv = g1[oc] * rsqrtf(va1[oc] + BN_EPS);
            cst[oc]      = inv;
            cst[32 + oc] = be1[oc] - mu1[oc] * inv;
        } else {
            float inv = g2[oc] * rsqrtf(va2[oc] + BN_EPS);
            cst[64 + oc] = inv;
            cst[96 + oc] = be2[oc] - mu2[oc] * inv;
        }
    }
    __syncthreads();

    // ---- phase 1: conv1 (circular pad 5, K=5x5x11=275) ----
    // wave w handles oc = 8w..8w+7 (uniform -> scalar weight loads);
    // lanes 0..49 cover (half, ow); patch value reused across 8 oc.
    {
        int wave = tid >> 6, lane = tid & 63;
        int oc0 = __builtin_amdgcn_readfirstlane(wave * 8);
        int l = (lane < 50) ? lane : 0;
        int half = (l >= 25) ? 1 : 0;
        int ow = l - half * 25;
        int pw[11];
#pragma unroll
        for (int kw = 0; kw < 11; ++kw) {
            int p = ow + kw - 5;
            if (p < 0) p += 25;
            if (p >= 25) p -= 25;
            pw[kw] = p;
        }
        float acc[8];
#pragma unroll
        for (int o = 0; o < 8; ++o) acc[o] = 0.f;
        for (int ic = 0; ic < 5; ++ic) {
            for (int kh = 0; kh < 5; ++kh) {
                const float* xp = &xh[((half * 5 + ic) * 5 + kh) * 25];
                const float* wp = w1 + oc0 * 275 + (ic * 5 + kh) * 11;
#pragma unroll
                for (int kw = 0; kw < 11; ++kw) {
                    float pv = xp[pw[kw]];
#pragma unroll
                    for (int o = 0; o < 8; ++o) acc[o] += pv * wp[o * 275 + kw];
                }
            }
        }
        if (lane < 50) {
#pragma unroll
            for (int o = 0; o < 8; ++o)
                h1[(half * 32 + oc0 + o) * 25 + ow] = acc[o] + b1[oc0 + o];
        }
    }
    __syncthreads();

    // ---- phase 2: a[n][m] = <h1[n], h1[m]>, leaky, store transposed aT[m][n] ----
    for (int e = tid; e < 2048; e += 256) {
        int half = e >> 10; int r = e & 1023;
        int m = r >> 5; int n = r & 31;
        const float* pn = &h1[(half * 32 + n) * 25];
        const float* pm = &h1[(half * 32 + m) * 25];
        float s = 0.f;
#pragma unroll
        for (int f = 0; f < 25; ++f) s += pn[f] * pm[f];
        s = (s > 0.f) ? s : ALPHA * s;
        aT[(half * 32 + m) * 33 + n] = s;
    }
    __syncthreads();

    // ---- phase 3: softmax over n (each row of aT), threads 0..63 ----
    if (tid < 64) {
        float* row = &aT[tid * 33];
        float mx = row[0];
#pragma unroll
        for (int n = 1; n < 32; ++n) mx = fmaxf(mx, row[n]);
        float s = 0.f;
#pragma unroll
        for (int n = 0; n < 32; ++n) s += __expf(row[n] - mx);
        float inv = 1.f / s;
#pragma unroll
        for (int n = 0; n < 32; ++n) row[n] = __expf(row[n] - mx) * inv;
    }
    __syncthreads();

    // ---- phase 4: out1[n][f] = sum_m att[n][m] * h1[m][f] ----
    for (int e = tid; e < 1600; e += 256) {
        int half = (e >= 800) ? 1 : 0;
        int r = e - half * 800;
        int n = r / 25; int f = r - n * 25;
        const float* av = &aT[half * 1056 + n];   // aT[half][m][n], stride 33
        const float* hv = &h1[half * 800 + f];    // h1[half][m][f], stride 25
        float s = 0.f;
#pragma unroll
        for (int m = 0; m < 32; ++m) s += av[m * 33] * hv[m * 25];
        out1[e] = s;  // layout [half][n][f] contiguous
    }
    __syncthreads();

    // ---- phase 5: bn1 + maxpool2 + relu -> p1[half][oc][j], j<12, stride 13 ----
    for (int e = tid; e < 768; e += 256) {
        int half = (e >= 384) ? 1 : 0;
        int r = e - half * 384;
        int oc = r / 12; int j = r - oc * 12;
        float inv = cst[oc], sh = cst[32 + oc];
        float v0 = out1[(half * 32 + oc) * 25 + 2 * j] * inv + sh;
        float v1 = out1[(half * 32 + oc) * 25 + 2 * j + 1] * inv + sh;
        p1[(half * 32 + oc) * 13 + j] = fmaxf(fmaxf(v0, v1), 0.f);
    }
    __syncthreads();

    // ---- phase 6: conv2 (circular pad 2, K=32x5=160) -> h2 (aliases h1) ----
    float* h2 = h1;
    {
        int wave = tid >> 6, lane = tid & 63;
        int oc0 = __builtin_amdgcn_readfirstlane(wave * 8);
        int l = (lane < 24) ? lane : 0;
        int half = (l >= 12) ? 1 : 0;
        int ow = l - half * 12;
        int jj[5];
#pragma unroll
        for (int kw = 0; kw < 5; ++kw) {
            int p = ow + kw - 2;
            if (p < 0) p += 12;
            if (p >= 12) p -= 12;
            jj[kw] = p;
        }
        float acc[8];
#pragma unroll
        for (int o = 0; o < 8; ++o) acc[o] = 0.f;
        for (int ic = 0; ic < 32; ++ic) {
            const float* pp = &p1[(half * 32 + ic) * 13];
            const float* wp = w2 + oc0 * 160 + ic * 5;
#pragma unroll
            for (int kw = 0; kw < 5; ++kw) {
                float pv = pp[jj[kw]];
#pragma unroll
                for (int o = 0; o < 8; ++o) acc[o] += pv * wp[o * 160 + kw];
            }
        }
        if (lane < 24) {
#pragma unroll
            for (int o = 0; o < 8; ++o)
                h2[(half * 32 + oc0 + o) * 13 + ow] = acc[o] + b2[oc0 + o];
        }
    }
    __syncthreads();

    // ---- phase 7: layer-2 attention scores (x2 uses <conv(xa),conv(na)>, n2 swapped) ----
    for (int e = tid; e < 2048; e += 256) {
        int half = e >> 10; int r = e & 1023;
        int m = r >> 5; int n = r & 31;
        const float* pn = &h2[(half * 32 + n) * 13];
        const float* pm = &h2[((1 - half) * 32 + m) * 13];
        float s = 0.f;
#pragma unroll
        for (int f = 0; f < 12; ++f) s += pn[f] * pm[f];
        s = (s > 0.f) ? s : ALPHA * s;
        aT[(half * 32 + m) * 33 + n] = s;
    }
    __syncthreads();

    // ---- phase 8: softmax ----
    if (tid < 64) {
        float* row = &aT[tid * 33];
        float mx = row[0];
#pragma unroll
        for (int n = 1; n < 32; ++n) mx = fmaxf(mx, row[n]);
        float s = 0.f;
#pragma unroll
        for (int n = 0; n < 32; ++n) s += __expf(row[n] - mx);
        float inv = 1.f / s;
#pragma unroll
        for (int n = 0; n < 32; ++n) row[n] = __expf(row[n] - mx) * inv;
    }
    __syncthreads();

    // ---- phase 9: o2[half][n][f] = sum_m att2[half][n][m] * h2[half][m][f] ----
    float* o2 = p1;  // p1 dead after conv2
    for (int e = tid; e < 768; e += 256) {
        int half = (e >= 384) ? 1 : 0;
        int r = e - half * 384;
        int n = r / 12; int f = r - n * 12;
        const float* av = &aT[half * 1056 + n];
        const float* hv = &h2[half * 416 + f];    // h2[half][m][f], stride 13
        float s = 0.f;
#pragma unroll
        for (int m = 0; m < 32; ++m) s += av[m * 33] * hv[m * 13];
        o2[(half * 32 + n) * 13 + f] = s;
    }
    __syncthreads();

    // ---- phase 10: bn2 + maxpool2 + relu -> p2 flat[384] (aliases xh) ----
    float* p2f = xh;
    for (int e = tid; e < 384; e += 256) {
        int n = e / 12; int rem = e - n * 12;
        int half = (rem >= 6) ? 1 : 0;
        int j = rem - half * 6;
        float inv = cst[64 + n], sh = cst[96 + n];
        float v0 = o2[(half * 32 + n) * 13 + 2 * j] * inv + sh;
        float v1 = o2[(half * 32 + n) * 13 + 2 * j + 1] * inv + sh;
        p2f[e] = fmaxf(fmaxf(v0, v1), 0.f);  // flat: n*12 + half*6 + j
    }
    __syncthreads();

    // ---- phase 11: linear 384 -> 13 ----
    if (tid < 104) {
        int o = tid >> 3; int s8 = tid & 7;
        const float* wv = lw + o * 384 + s8 * 48;
        const float* fv = p2f + s8 * 48;
        float s = 0.f;
#pragma unroll
        for (int i = 0; i < 48; ++i) s += fv[i] * wv[i];
        s += __shfl_down(s, 4, 8);
        s += __shfl_down(s, 2, 8);
        s += __shfl_down(s, 1, 8);
        if (s8 == 0) out[(size_t)b * 13 + o] = s + lb[o];
    }
}

extern "C" void kernel_launch(void* const* d_in, const int* in_sizes, int n_in,
                              void* d_out, int out_size, void* d_ws, size_t ws_size,
                              hipStream_t stream) {
    const float* x   = (const float*)d_in[0];
    const float* w1  = (const float*)d_in[1];
    const float* b1  = (const float*)d_in[2];
    const float* g1  = (const float*)d_in[3];
    const float* be1 = (const float*)d_in[4];
    const float* mu1 = (const float*)d_in[5];
    const float* va1 = (const float*)d_in[6];
    const float* w2  = (const float*)d_in[7];
    const float* b2  = (const float*)d_in[8];
    const float* g2  = (const float*)d_in[9];
    const float* be2 = (const float*)d_in[10];
    const float* mu2 = (const float*)d_in[11];
    const float* va2 = (const float*)d_in[12];
    const float* lw  = (const float*)d_in[13];
    const float* lb  = (const float*)d_in[14];
    float* out = (float*)d_out;

    int B = in_sizes[0] / 1250;  // 16384
    gcn_kernel<<<B, 256, 0, stream>>>(x, w1, b1, g1, be1, mu1, va1,
                                      w2, b2, g2, be2, mu2, va2, lw, lb, out);
}

// Round 3
// 1053.738 us; speedup vs baseline: 1.0510x; 1.0510x over previous
//
#include <hip/hip_runtime.h>
#include <math.h>

#define ALPHA 0.2f
#define BN_EPS 1e-5f

// LDS layout (floats):
//   xh   [2][5][5][25]  = 1250   @0      (reused as p2f[384] after conv1)
//   cst  inv1/sh1/inv2/sh2 [4][32] = 128 @1250
//   h1   [2][32][25]    = 1600   @1378   (reused as h2 [2][32][13]=832)
//   aT   [2][32][33]    = 2112   @2978   (rows padded to 33 vs 64-lane bank hit)
//   p1   [2][32][13]    = 832    @5090   (stride 13 to dodge gcd(12,32) aliasing)
// total 5922 floats = 23.7 KB
// NOTE: no waves-per-EU clamp — round 2's (256,5) forced VGPR<=96 and spilled
// pn[25]/ev[8] to scratch; scratch + hipGraph replay produced deterministic
// post-capture corruption. Plain launch_bounds(256) like round 1 (stable).
#define LDS_TOTAL 5922

__global__ __launch_bounds__(256) void gcn_kernel(
    const float* __restrict__ x,
    const float* __restrict__ w1, const float* __restrict__ b1,
    const float* __restrict__ g1, const float* __restrict__ be1,
    const float* __restrict__ mu1, const float* __restrict__ va1,
    const float* __restrict__ w2, const float* __restrict__ b2,
    const float* __restrict__ g2, const float* __restrict__ be2,
    const float* __restrict__ mu2, const float* __restrict__ va2,
    const float* __restrict__ lw, const float* __restrict__ lb,
    float* __restrict__ out)
{
    __shared__ float lds[LDS_TOTAL];
    float* xh   = lds;          // 1250
    float* cst  = lds + 1250;   // 128
    float* h1   = lds + 1378;   // 1600 (h2 alias)
    float* aT   = lds + 2978;   // 2112
    float* p1   = lds + 5090;   // 832

    const int tid = threadIdx.x;
    const int b   = blockIdx.x;
    const float* xg = x + (size_t)b * 1250;

    // ---- phase 0: load input, precompute BN constants ----
    for (int i = tid; i < 1250; i += 256) {
        int c = i / 250; int r = i - c * 250;
        int h = r / 50;  int w50 = r - h * 50;
        int half = (w50 >= 25) ? 1 : 0;
        int w = w50 - half * 25;
        xh[((half * 5 + c) * 5 + h) * 25 + w] = xg[i];
    }
    if (tid < 64) {
        int oc = tid & 31;
        if (tid < 32) {
            float inv = g1[oc] * rsqrtf(va1[oc] + BN_EPS);
            cst[oc]      = inv;
            cst[32 + oc] = be1[oc] - mu1[oc] * inv;
        } else {
            float inv = g2[oc] * rsqrtf(va2[oc] + BN_EPS);
            cst[64 + oc] = inv;
            cst[96 + oc] = be2[oc] - mu2[oc] * inv;
        }
    }
    __syncthreads();

    // ---- phase 1: conv1 (circular pad 5, K=5x5x11=275) ----
    // wave w -> oc 8w..8w+7 (uniform -> scalar weight loads);
    // lanes 0..49 cover (half, ow); patch value feeds 8 FMA.
    {
        int wave = tid >> 6, lane = tid & 63;
        int oc0 = __builtin_amdgcn_readfirstlane(wave * 8);
        int l = (lane < 50) ? lane : 0;
        int half = (l >= 25) ? 1 : 0;
        int ow = l - half * 25;
        int pw[11];
#pragma unroll
        for (int kw = 0; kw < 11; ++kw) {
            int p = ow + kw - 5;
            if (p < 0) p += 25;
            if (p >= 25) p -= 25;
            pw[kw] = p;
        }
        float acc[8];
#pragma unroll
        for (int o = 0; o < 8; ++o) acc[o] = 0.f;
        for (int ic = 0; ic < 5; ++ic) {
            for (int kh = 0; kh < 5; ++kh) {
                const float* xp = &xh[((half * 5 + ic) * 5 + kh) * 25];
                const float* wp = w1 + oc0 * 275 + (ic * 5 + kh) * 11;
#pragma unroll
                for (int kw = 0; kw < 11; ++kw) {
                    float pv = xp[pw[kw]];
#pragma unroll
                    for (int o = 0; o < 8; ++o) acc[o] += pv * wp[o * 275 + kw];
                }
            }
        }
        if (lane < 50) {
#pragma unroll
            for (int o = 0; o < 8; ++o)
                h1[(half * 32 + oc0 + o) * 25 + ow] = acc[o] + b1[oc0 + o];
        }
    }
    __syncthreads();

    // ---- phase 2: scores a[n][m] = <h1[n],h1[m]>, leaky, store aT[m][n] ----
    // thread: fixed n = tid&31 (register-caches its row), group picks 4 m's.
    {
        int n = tid & 31, grp = tid >> 5;
#pragma unroll
        for (int half = 0; half < 2; ++half) {
            float pn[25];
            const float* bp = &h1[(half * 32 + n) * 25];
#pragma unroll
            for (int f = 0; f < 25; ++f) pn[f] = bp[f];
#pragma unroll
            for (int i = 0; i < 4; ++i) {
                int m = grp * 4 + i;
                const float* pm = &h1[(half * 32 + m) * 25];  // broadcast per group
                float s = 0.f;
#pragma unroll
                for (int f = 0; f < 25; ++f) s += pn[f] * pm[f];
                s = (s > 0.f) ? s : ALPHA * s;
                aT[(half * 32 + m) * 33 + n] = s;
            }
        }
    }
    __syncthreads();

    // ---- phase 3: softmax over n, all 256 threads (64 rows x 4 lanes) ----
    {
        int row = tid >> 2, q = tid & 3;
        float* rp = &aT[row * 33];
        float ev[8];
        float mx = -INFINITY;
#pragma unroll
        for (int k = 0; k < 8; ++k) { ev[k] = rp[q + 4 * k]; mx = fmaxf(mx, ev[k]); }
        mx = fmaxf(mx, __shfl_xor(mx, 1));
        mx = fmaxf(mx, __shfl_xor(mx, 2));
        float s = 0.f;
#pragma unroll
        for (int k = 0; k < 8; ++k) { ev[k] = __expf(ev[k] - mx); s += ev[k]; }
        s += __shfl_xor(s, 1);
        s += __shfl_xor(s, 2);
        float inv = 1.f / s;
#pragma unroll
        for (int k = 0; k < 8; ++k) rp[q + 4 * k] = ev[k] * inv;
    }
    __syncthreads();

    // ---- phase 4+5 fused: (att @ h1) -> bn1 -> maxpool2 -> relu -> p1 ----
    for (int e = tid; e < 768; e += 256) {
        int half = (e >= 384) ? 1 : 0;
        int r = e - half * 384;
        int n = r / 12, j = r - n * 12;
        const float* av = &aT[half * 1056 + n];      // att[n][m] = aT[m*33+n]
        const float* hv = &h1[half * 800 + 2 * j];   // h1[m][2j], stride 25
        float s0 = 0.f, s1 = 0.f;
#pragma unroll
        for (int m = 0; m < 32; ++m) {
            float a = av[m * 33];
            s0 += a * hv[m * 25];
            s1 += a * hv[m * 25 + 1];
        }
        float inv = cst[n], sh = cst[32 + n];
        float v0 = s0 * inv + sh, v1 = s1 * inv + sh;
        p1[(half * 32 + n) * 13 + j] = fmaxf(fmaxf(v0, v1), 0.f);
    }
    __syncthreads();

    // ---- phase 6: conv2 (circular pad 2, K=32x5=160) -> h2 (aliases h1) ----
    float* h2 = h1;
    {
        int wave = tid >> 6, lane = tid & 63;
        int oc0 = __builtin_amdgcn_readfirstlane(wave * 8);
        int l = (lane < 24) ? lane : 0;
        int half = (l >= 12) ? 1 : 0;
        int ow = l - half * 12;
        int jj[5];
#pragma unroll
        for (int kw = 0; kw < 5; ++kw) {
            int p = ow + kw - 2;
            if (p < 0) p += 12;
            if (p >= 12) p -= 12;
            jj[kw] = p;
        }
        float acc[8];
#pragma unroll
        for (int o = 0; o < 8; ++o) acc[o] = 0.f;
        for (int ic = 0; ic < 32; ++ic) {
            const float* pp = &p1[(half * 32 + ic) * 13];
            const float* wp = w2 + oc0 * 160 + ic * 5;
#pragma unroll
            for (int kw = 0; kw < 5; ++kw) {
                float pv = pp[jj[kw]];
#pragma unroll
                for (int o = 0; o < 8; ++o) acc[o] += pv * wp[o * 160 + kw];
            }
        }
        if (lane < 24) {
#pragma unroll
            for (int o = 0; o < 8; ++o)
                h2[(half * 32 + oc0 + o) * 13 + ow] = acc[o] + b2[oc0 + o];
        }
    }
    __syncthreads();

    // ---- phase 7: layer-2 scores (x2: <conv(xa),conv(na)>; n2 swapped) ----
    {
        int n = tid & 31, grp = tid >> 5;
#pragma unroll
        for (int half = 0; half < 2; ++half) {
            float pn[12];
            const float* bp = &h2[(half * 32 + n) * 13];
#pragma unroll
            for (int f = 0; f < 12; ++f) pn[f] = bp[f];
#pragma unroll
            for (int i = 0; i < 4; ++i) {
                int m = grp * 4 + i;
                const float* pm = &h2[((1 - half) * 32 + m) * 13];
                float s = 0.f;
#pragma unroll
                for (int f = 0; f < 12; ++f) s += pn[f] * pm[f];
                s = (s > 0.f) ? s : ALPHA * s;
                aT[(half * 32 + m) * 33 + n] = s;
            }
        }
    }
    __syncthreads();

    // ---- phase 8: softmax ----
    {
        int row = tid >> 2, q = tid & 3;
        float* rp = &aT[row * 33];
        float ev[8];
        float mx = -INFINITY;
#pragma unroll
        for (int k = 0; k < 8; ++k) { ev[k] = rp[q + 4 * k]; mx = fmaxf(mx, ev[k]); }
        mx = fmaxf(mx, __shfl_xor(mx, 1));
        mx = fmaxf(mx, __shfl_xor(mx, 2));
        float s = 0.f;
#pragma unroll
        for (int k = 0; k < 8; ++k) { ev[k] = __expf(ev[k] - mx); s += ev[k]; }
        s += __shfl_xor(s, 1);
        s += __shfl_xor(s, 2);
        float inv = 1.f / s;
#pragma unroll
        for (int k = 0; k < 8; ++k) rp[q + 4 * k] = ev[k] * inv;
    }
    __syncthreads();

    // ---- phase 9+10 fused: (att2 @ h2) -> bn2 -> pool -> relu -> p2f ----
    float* p2f = xh;  // xh dead since conv1
    for (int e = tid; e < 384; e += 256) {
        int n = e / 12; int rem = e - n * 12;
        int half = (rem >= 6) ? 1 : 0;
        int j = rem - half * 6;
        const float* av = &aT[half * 1056 + n];
        const float* hv = &h2[half * 416 + 2 * j];   // h2[m][2j], stride 13
        float s0 = 0.f, s1 = 0.f;
#pragma unroll
        for (int m = 0; m < 32; ++m) {
            float a = av[m * 33];
            s0 += a * hv[m * 13];
            s1 += a * hv[m * 13 + 1];
        }
        float inv = cst[64 + n], sh = cst[96 + n];
        p2f[e] = fmaxf(fmaxf(s0 * inv + sh, s1 * inv + sh), 0.f);
    }
    __syncthreads();

    // ---- phase 11: linear 384 -> 13 ----
    if (tid < 104) {
        int o = tid >> 3; int s8 = tid & 7;
        const float* wv = lw + o * 384 + s8 * 48;
        const float* fv = p2f + s8 * 48;
        float s = 0.f;
#pragma unroll
        for (int i = 0; i < 48; ++i) s += fv[i] * wv[i];
        s += __shfl_down(s, 4, 8);
        s += __shfl_down(s, 2, 8);
        s += __shfl_down(s, 1, 8);
        if (s8 == 0) out[(size_t)b * 13 + o] = s + lb[o];
    }
}

extern "C" void kernel_launch(void* const* d_in, const int* in_sizes, int n_in,
                              void* d_out, int out_size, void* d_ws, size_t ws_size,
                              hipStream_t stream) {
    const float* x   = (const float*)d_in[0];
    const float* w1  = (const float*)d_in[1];
    const float* b1  = (const float*)d_in[2];
    const float* g1  = (const float*)d_in[3];
    const float* be1 = (const float*)d_in[4];
    const float* mu1 = (const float*)d_in[5];
    const float* va1 = (const float*)d_in[6];
    const float* w2  = (const float*)d_in[7];
    const float* b2  = (const float*)d_in[8];
    const float* g2  = (const float*)d_in[9];
    const float* be2 = (const float*)d_in[10];
    const float* mu2 = (const float*)d_in[11];
    const float* va2 = (const float*)d_in[12];
    const float* lw  = (const float*)d_in[13];
    const float* lb  = (const float*)d_in[14];
    float* out = (float*)d_out;

    int B = in_sizes[0] / 1250;  // 16384
    gcn_kernel<<<B, 256, 0, stream>>>(x, w1, b1, g1, be1, mu1, va1,
                                      w2, b2, g2, be2, mu2, va2, lw, lb, out);
}

// Round 4
// 872.816 us; speedup vs baseline: 1.2689x; 1.2073x over previous
//
#include <hip/hip_runtime.h>
#include <math.h>

#define ALPHA 0.2f
#define BN_EPS 1e-5f

// Two batch items per block. Per-item LDS region (stride IT=4544 floats):
//   [0,2112)   : xh [2][5][5][25]=1250 (phases 0-1), then aT [2][32][33]=2112
//                (phases 2-9; xh dead after conv1). aT rows padded to 33.
//   [2112,3712): h1 [2][32][25]=1600 (h2 [2][32][13]=832 aliases, phase 6+)
//   [3712,4544): p1 [2][32][13]=832 (conv2 input; p2f[384] aliases, phase 9+)
// cst @ 9088: inv1/sh1/inv2/sh2 [4][32]=128
// total 9216 floats = 36.9 KB -> 4 blocks/CU (147.5 of 160 KB)
#define IT 4544
#define H1O 2112
#define P1O 3712
#define CSTO 9088
#define LDS_TOTAL 9216

__global__ __launch_bounds__(256) void gcn_kernel(
    const float* __restrict__ x,
    const float* __restrict__ w1, const float* __restrict__ b1,
    const float* __restrict__ g1, const float* __restrict__ be1,
    const float* __restrict__ mu1, const float* __restrict__ va1,
    const float* __restrict__ w2, const float* __restrict__ b2,
    const float* __restrict__ g2, const float* __restrict__ be2,
    const float* __restrict__ mu2, const float* __restrict__ va2,
    const float* __restrict__ lw, const float* __restrict__ lb,
    float* __restrict__ out)
{
    __shared__ float lds[LDS_TOTAL];
    float* cst = lds + CSTO;

    const int tid = threadIdx.x;
    const int b0  = blockIdx.x * 2;

    // ---- phase 0: load 2 items (2500 contiguous floats), remap; BN consts ----
    for (int i = tid; i < 2500; i += 256) {
        int it = (i >= 1250) ? 1 : 0;
        int j = i - it * 1250;
        int c = j / 250; int r = j - c * 250;
        int h = r / 50;  int w50 = r - h * 50;
        int half = (w50 >= 25) ? 1 : 0;
        int w = w50 - half * 25;
        lds[it * IT + ((half * 5 + c) * 5 + h) * 25 + w] = x[(size_t)b0 * 1250 + i];
    }
    if (tid < 64) {
        int oc = tid & 31;
        if (tid < 32) {
            float inv = g1[oc] * rsqrtf(va1[oc] + BN_EPS);
            cst[oc]      = inv;
            cst[32 + oc] = be1[oc] - mu1[oc] * inv;
        } else {
            float inv = g2[oc] * rsqrtf(va2[oc] + BN_EPS);
            cst[64 + oc] = inv;
            cst[96 + oc] = be2[oc] - mu2[oc] * inv;
        }
    }
    __syncthreads();

    // ---- phase 1: conv1 (circular pad 5, K=275) ----
    // wave -> (item = w>>1, oc-range 16*(w&1)); lanes 0..49 = (half, ow).
    {
        int wave = tid >> 6, lane = tid & 63;
        int it = wave >> 1;
        int oc0 = __builtin_amdgcn_readfirstlane((wave & 1) * 16);
        const float* xbase = &lds[it * IT];
        float* hout = &lds[it * IT + H1O];
        int l = (lane < 50) ? lane : 0;
        int half = (l >= 25) ? 1 : 0;
        int ow = l - half * 25;
        int pw[11];
#pragma unroll
        for (int kw = 0; kw < 11; ++kw) {
            int p = ow + kw - 5;
            if (p < 0) p += 25;
            if (p >= 25) p -= 25;
            pw[kw] = p;
        }
        float acc[16];
#pragma unroll
        for (int o = 0; o < 16; ++o) acc[o] = 0.f;
        for (int ic = 0; ic < 5; ++ic) {
            for (int kh = 0; kh < 5; ++kh) {
                const float* xp = xbase + ((half * 5 + ic) * 5 + kh) * 25;
                const float* wp = w1 + oc0 * 275 + (ic * 5 + kh) * 11;
#pragma unroll
                for (int kw = 0; kw < 11; ++kw) {
                    float pv = xp[pw[kw]];
#pragma unroll
                    for (int o = 0; o < 16; ++o) acc[o] += pv * wp[o * 275 + kw];
                }
            }
        }
        if (lane < 50) {
#pragma unroll
            for (int o = 0; o < 16; ++o)
                hout[(half * 32 + oc0 + o) * 25 + ow] = acc[o] + b1[oc0 + o];
        }
    }
    __syncthreads();

    // ---- phase 2: scores a[n][m]=<h1[n],h1[m]>, leaky -> aT[m][n] (over xh) ----
    // thread: n = tid&31; group (tid>>5) -> (item, m-octet).
    {
        int n = tid & 31, grp = tid >> 5;
        int it = grp >> 2, mq = grp & 3;
        const float* H = &lds[it * IT + H1O];
        float* A = &lds[it * IT];
#pragma unroll
        for (int half = 0; half < 2; ++half) {
            float pn[25];
            const float* bp = &H[(half * 32 + n) * 25];
#pragma unroll
            for (int f = 0; f < 25; ++f) pn[f] = bp[f];
#pragma unroll
            for (int i = 0; i < 8; ++i) {
                int m = mq * 8 + i;
                const float* pm = &H[(half * 32 + m) * 25];
                float s = 0.f;
#pragma unroll
                for (int f = 0; f < 25; ++f) s += pn[f] * pm[f];
                s = (s > 0.f) ? s : ALPHA * s;
                A[(half * 32 + m) * 33 + n] = s;
            }
        }
    }
    __syncthreads();

    // ---- phase 3: softmax over n; 128 rows x 2 lanes ----
    {
        int row = tid >> 1, q = tid & 1;
        int it = row >> 6, rm = row & 63;
        float* rp = &lds[it * IT + rm * 33];
        float ev[16];
        float mx = -INFINITY;
#pragma unroll
        for (int k = 0; k < 16; ++k) { ev[k] = rp[q + 2 * k]; mx = fmaxf(mx, ev[k]); }
        mx = fmaxf(mx, __shfl_xor(mx, 1));
        float s = 0.f;
#pragma unroll
        for (int k = 0; k < 16; ++k) { ev[k] = __expf(ev[k] - mx); s += ev[k]; }
        s += __shfl_xor(s, 1);
        float inv = 1.f / s;
#pragma unroll
        for (int k = 0; k < 16; ++k) rp[q + 2 * k] = ev[k] * inv;
    }
    __syncthreads();

    // ---- phase 4+5: (att @ h1) -> bn1 -> maxpool2 -> relu -> p1 ----
    for (int e = tid; e < 1536; e += 256) {
        int it = (e >= 768) ? 1 : 0;
        int r = e - it * 768;
        int half = (r >= 384) ? 1 : 0;
        int r2 = r - half * 384;
        int n = r2 / 12, j = r2 - n * 12;
        const float* A  = &lds[it * IT + half * 1056 + n];
        const float* hv = &lds[it * IT + H1O + half * 800 + 2 * j];
        float s0 = 0.f, s1 = 0.f;
#pragma unroll
        for (int m = 0; m < 32; ++m) {
            float a = A[m * 33];
            s0 += a * hv[m * 25];
            s1 += a * hv[m * 25 + 1];
        }
        float inv = cst[n], sh = cst[32 + n];
        float v0 = s0 * inv + sh, v1 = s1 * inv + sh;
        lds[it * IT + P1O + (half * 32 + n) * 13 + j] = fmaxf(fmaxf(v0, v1), 0.f);
    }
    __syncthreads();

    // ---- phase 6: conv2 (circular pad 2, K=160) -> h2 (over h1) ----
    // wave -> oc 8w..8w+7; lanes 0..47 = (item, half, ow): 2x lane util vs 1-item.
    {
        int wave = tid >> 6, lane = tid & 63;
        int oc0 = __builtin_amdgcn_readfirstlane(wave * 8);
        int l = (lane < 48) ? lane : 0;
        int it = (l >= 24) ? 1 : 0;
        int r = l - it * 24;
        int half = (r >= 12) ? 1 : 0;
        int ow = r - half * 12;
        const float* pbase = &lds[it * IT + P1O];
        float* hout = &lds[it * IT + H1O];
        int jj[5];
#pragma unroll
        for (int kw = 0; kw < 5; ++kw) {
            int p = ow + kw - 2;
            if (p < 0) p += 12;
            if (p >= 12) p -= 12;
            jj[kw] = p;
        }
        float acc[8];
#pragma unroll
        for (int o = 0; o < 8; ++o) acc[o] = 0.f;
        for (int ic = 0; ic < 32; ++ic) {
            const float* pp = pbase + (half * 32 + ic) * 13;
            const float* wp = w2 + oc0 * 160 + ic * 5;
#pragma unroll
            for (int kw = 0; kw < 5; ++kw) {
                float pv = pp[jj[kw]];
#pragma unroll
                for (int o = 0; o < 8; ++o) acc[o] += pv * wp[o * 160 + kw];
            }
        }
        if (lane < 48) {
#pragma unroll
            for (int o = 0; o < 8; ++o)
                hout[(half * 32 + oc0 + o) * 13 + ow] = acc[o] + b2[oc0 + o];
        }
    }
    __syncthreads();

    // ---- phase 7: layer-2 scores (n-side: conv of own half; m-side: other half) ----
    {
        int n = tid & 31, grp = tid >> 5;
        int it = grp >> 2, mq = grp & 3;
        const float* H = &lds[it * IT + H1O];  // h2
        float* A = &lds[it * IT];
#pragma unroll
        for (int half = 0; half < 2; ++half) {
            float pn[12];
            const float* bp = &H[(half * 32 + n) * 13];
#pragma unroll
            for (int f = 0; f < 12; ++f) pn[f] = bp[f];
#pragma unroll
            for (int i = 0; i < 8; ++i) {
                int m = mq * 8 + i;
                const float* pm = &H[((1 - half) * 32 + m) * 13];
                float s = 0.f;
#pragma unroll
                for (int f = 0; f < 12; ++f) s += pn[f] * pm[f];
                s = (s > 0.f) ? s : ALPHA * s;
                A[(half * 32 + m) * 33 + n] = s;
            }
        }
    }
    __syncthreads();

    // ---- phase 8: softmax ----
    {
        int row = tid >> 1, q = tid & 1;
        int it = row >> 6, rm = row & 63;
        float* rp = &lds[it * IT + rm * 33];
        float ev[16];
        float mx = -INFINITY;
#pragma unroll
        for (int k = 0; k < 16; ++k) { ev[k] = rp[q + 2 * k]; mx = fmaxf(mx, ev[k]); }
        mx = fmaxf(mx, __shfl_xor(mx, 1));
        float s = 0.f;
#pragma unroll
        for (int k = 0; k < 16; ++k) { ev[k] = __expf(ev[k] - mx); s += ev[k]; }
        s += __shfl_xor(s, 1);
        float inv = 1.f / s;
#pragma unroll
        for (int k = 0; k < 16; ++k) rp[q + 2 * k] = ev[k] * inv;
    }
    __syncthreads();

    // ---- phase 9+10: (att2 @ h2) -> bn2 -> pool -> relu -> p2f (over p1) ----
    for (int e = tid; e < 768; e += 256) {
        int it = (e >= 384) ? 1 : 0;
        int r = e - it * 384;
        int n = r / 12; int rem = r - n * 12;
        int half = (rem >= 6) ? 1 : 0;
        int j = rem - half * 6;
        const float* A  = &lds[it * IT + half * 1056 + n];
        const float* hv = &lds[it * IT + H1O + half * 416 + 2 * j];
        float s0 = 0.f, s1 = 0.f;
#pragma unroll
        for (int m = 0; m < 32; ++m) {
            float a = A[m * 33];
            s0 += a * hv[m * 13];
            s1 += a * hv[m * 13 + 1];
        }
        float inv = cst[64 + n], sh = cst[96 + n];
        lds[it * IT + P1O + r] = fmaxf(fmaxf(s0 * inv + sh, s1 * inv + sh), 0.f);
    }
    __syncthreads();

    // ---- phase 11: linear 384 -> 13, both items (208 threads) ----
    if (tid < 208) {
        int s8 = tid & 7;
        int rest = tid >> 3;             // 0..25
        int it = (rest >= 13) ? 1 : 0;
        int o = rest - it * 13;
        const float* wv = lw + o * 384 + s8 * 48;
        const float* fv = &lds[it * IT + P1O + s8 * 48];
        float s = 0.f;
#pragma unroll
        for (int i = 0; i < 48; ++i) s += fv[i] * wv[i];
        s += __shfl_down(s, 4, 8);
        s += __shfl_down(s, 2, 8);
        s += __shfl_down(s, 1, 8);
        if (s8 == 0) out[(size_t)(b0 + it) * 13 + o] = s + lb[o];
    }
}

extern "C" void kernel_launch(void* const* d_in, const int* in_sizes, int n_in,
                              void* d_out, int out_size, void* d_ws, size_t ws_size,
                              hipStream_t stream) {
    const float* x   = (const float*)d_in[0];
    const float* w1  = (const float*)d_in[1];
    const float* b1  = (const float*)d_in[2];
    const float* g1  = (const float*)d_in[3];
    const float* be1 = (const float*)d_in[4];
    const float* mu1 = (const float*)d_in[5];
    const float* va1 = (const float*)d_in[6];
    const float* w2  = (const float*)d_in[7];
    const float* b2  = (const float*)d_in[8];
    const float* g2  = (const float*)d_in[9];
    const float* be2 = (const float*)d_in[10];
    const float* mu2 = (const float*)d_in[11];
    const float* va2 = (const float*)d_in[12];
    const float* lw  = (const float*)d_in[13];
    const float* lb  = (const float*)d_in[14];
    float* out = (float*)d_out;

    int B = in_sizes[0] / 1250;  // 16384
    gcn_kernel<<<B / 2, 256, 0, stream>>>(x, w1, b1, g1, be1, mu1, va1,
                                          w2, b2, g2, be2, mu2, va2, lw, lb, out);
}

// Round 5
// 857.162 us; speedup vs baseline: 1.2921x; 1.0183x over previous
//
#include <hip/hip_runtime.h>
#include <math.h>

#define ALPHA 0.2f
#define BN_EPS 1e-5f

// Two batch items per block. Per-item LDS region (stride IT=4648 floats,
// IT % 32 == 8 so the two items' regions are bank-staggered):
//   [0,2112)    : xh [2][5][5][25]=1250 (phases 0-1), then aT [2][32][33]=2112
//   [2112,3776) : h1 [2][32][26]=1664, row stride 26 (even -> ds_read_b64-able)
//                 (h2 [half*432 + oc*13 + ow]=864 aliases from phase 6)
//   [3776,4640) : p1 [half*432 + ic*13 + j]=864 (p2f[384] flat aliases, ph 9+)
// half-strides 432 (%32==16) + IT (%32==8) give conv2's four (it,half) lane
// groups bank offsets {0,16,8,24} -> max 2-way (free) instead of 4-way.
// cst @ 9296: inv1/sh1/inv2/sh2 [4][32]=128
// total 9424 floats = 37.7 KB -> 4 blocks/CU
#define IT 4648
#define H1O 2112
#define P1O 3776
#define CSTO 9296
#define LDS_TOTAL 9424

__global__ __launch_bounds__(256) void gcn_kernel(
    const float* __restrict__ x,
    const float* __restrict__ w1, const float* __restrict__ b1,
    const float* __restrict__ g1, const float* __restrict__ be1,
    const float* __restrict__ mu1, const float* __restrict__ va1,
    const float* __restrict__ w2, const float* __restrict__ b2,
    const float* __restrict__ g2, const float* __restrict__ be2,
    const float* __restrict__ mu2, const float* __restrict__ va2,
    const float* __restrict__ lw, const float* __restrict__ lb,
    float* __restrict__ out)
{
    __shared__ float lds[LDS_TOTAL];
    float* cst = lds + CSTO;

    const int tid = threadIdx.x;
    const int b0  = blockIdx.x * 2;

    // ---- phase 0: load 2 items as float2 (2500 floats), remap; BN consts ----
    {
        const float2* xg2 = (const float2*)(x + (size_t)b0 * 1250);
        for (int i2 = tid; i2 < 1250; i2 += 256) {
            float2 v = xg2[i2];
            int i = 2 * i2;
            int it = (i >= 1250) ? 1 : 0;
            int j = i - it * 1250;          // even
            int c = j / 250; int r = j - c * 250;
            int h = r / 50;  int w50 = r - h * 50;   // even, <= 48
            // element 0: w50; element 1: w50+1 (same c,h)
            int ha = (w50 >= 25) ? 1 : 0;
            lds[it * IT + ((ha * 5 + c) * 5 + h) * 25 + (w50 - ha * 25)] = v.x;
            int w51 = w50 + 1;
            int hb = (w51 >= 25) ? 1 : 0;
            lds[it * IT + ((hb * 5 + c) * 5 + h) * 25 + (w51 - hb * 25)] = v.y;
        }
    }
    if (tid < 64) {
        int oc = tid & 31;
        if (tid < 32) {
            float inv = g1[oc] * rsqrtf(va1[oc] + BN_EPS);
            cst[oc]      = inv;
            cst[32 + oc] = be1[oc] - mu1[oc] * inv;
        } else {
            float inv = g2[oc] * rsqrtf(va2[oc] + BN_EPS);
            cst[64 + oc] = inv;
            cst[96 + oc] = be2[oc] - mu2[oc] * inv;
        }
    }
    __syncthreads();

    // ---- phase 1: conv1 (circular pad 5, K=275) ----
    // wave -> (item = w>>1, oc0 = 16*(w&1)); lanes 0..49 = (half, ow).
    {
        int wave = tid >> 6, lane = tid & 63;
        int it = wave >> 1;
        int oc0 = __builtin_amdgcn_readfirstlane((wave & 1) * 16);
        const float* xbase = &lds[it * IT];
        float* hout = &lds[it * IT + H1O];
        int l = (lane < 50) ? lane : 0;
        int half = (l >= 25) ? 1 : 0;
        int ow = l - half * 25;
        int pw[11];
#pragma unroll
        for (int kw = 0; kw < 11; ++kw) {
            int p = ow + kw - 5;
            if (p < 0) p += 25;
            if (p >= 25) p -= 25;
            pw[kw] = p;
        }
        float acc[16];
#pragma unroll
        for (int o = 0; o < 16; ++o) acc[o] = 0.f;
        for (int ic = 0; ic < 5; ++ic) {
            for (int kh = 0; kh < 5; ++kh) {
                const float* xp = xbase + ((half * 5 + ic) * 5 + kh) * 25;
                const float* wp = w1 + oc0 * 275 + (ic * 5 + kh) * 11;
#pragma unroll
                for (int kw = 0; kw < 11; ++kw) {
                    float pv = xp[pw[kw]];
#pragma unroll
                    for (int o = 0; o < 16; ++o) acc[o] += pv * wp[o * 275 + kw];
                }
            }
        }
        if (lane < 50) {
#pragma unroll
            for (int o = 0; o < 16; ++o)
                hout[(half * 32 + oc0 + o) * 26 + ow] = acc[o] + b1[oc0 + o];
        }
    }
    __syncthreads();

    // ---- phase 2: scores a[n][m]=<h1[n],h1[m]>, leaky -> aT[m][n] (over xh) ----
    // thread: n = tid&31; group (tid>>5) -> (item, m-octet). b64 row loads.
    {
        int n = tid & 31, grp = tid >> 5;
        int it = grp >> 2, mq = grp & 3;
        const float* H = &lds[it * IT + H1O];
        float* A = &lds[it * IT];
#pragma unroll
        for (int half = 0; half < 2; ++half) {
            float pn[25];
            const float* bp = &H[(half * 32 + n) * 26];
            const float2* bp2 = (const float2*)bp;
#pragma unroll
            for (int f2 = 0; f2 < 12; ++f2) {
                float2 v = bp2[f2];
                pn[2 * f2] = v.x; pn[2 * f2 + 1] = v.y;
            }
            pn[24] = bp[24];
#pragma unroll
            for (int i = 0; i < 8; ++i) {
                int m = mq * 8 + i;
                const float* pm = &H[(half * 32 + m) * 26];
                const float2* pm2 = (const float2*)pm;
                float s = 0.f;
#pragma unroll
                for (int f2 = 0; f2 < 12; ++f2) {
                    float2 v = pm2[f2];
                    s += pn[2 * f2] * v.x + pn[2 * f2 + 1] * v.y;
                }
                s += pn[24] * pm[24];
                s = (s > 0.f) ? s : ALPHA * s;
                A[(half * 32 + m) * 33 + n] = s;
            }
        }
    }
    __syncthreads();

    // ---- phase 3: softmax over n; 128 rows x 2 lanes ----
    {
        int row = tid >> 1, q = tid & 1;
        int it = row >> 6, rm = row & 63;
        float* rp = &lds[it * IT + rm * 33];
        float ev[16];
        float mx = -INFINITY;
#pragma unroll
        for (int k = 0; k < 16; ++k) { ev[k] = rp[q + 2 * k]; mx = fmaxf(mx, ev[k]); }
        mx = fmaxf(mx, __shfl_xor(mx, 1));
        float s = 0.f;
#pragma unroll
        for (int k = 0; k < 16; ++k) { ev[k] = __expf(ev[k] - mx); s += ev[k]; }
        s += __shfl_xor(s, 1);
        float inv = 1.f / s;
#pragma unroll
        for (int k = 0; k < 16; ++k) rp[q + 2 * k] = ev[k] * inv;
    }
    __syncthreads();

    // ---- phase 4+5: (att @ h1) -> bn1 -> maxpool2 -> relu -> p1 ----
    for (int e = tid; e < 1536; e += 256) {
        int it = (e >= 768) ? 1 : 0;
        int r = e - it * 768;
        int half = (r >= 384) ? 1 : 0;
        int r2 = r - half * 384;
        int n = r2 / 12, j = r2 - n * 12;
        const float* A = &lds[it * IT + half * 1056 + n];
        const float2* hv2 = (const float2*)&lds[it * IT + H1O + half * 832 + 2 * j];
        float s0 = 0.f, s1 = 0.f;
#pragma unroll
        for (int m = 0; m < 32; ++m) {
            float a = A[m * 33];
            float2 v = hv2[m * 13];          // h1[m][2j], h1[m][2j+1]
            s0 += a * v.x;
            s1 += a * v.y;
        }
        float inv = cst[n], sh = cst[32 + n];
        float v0 = s0 * inv + sh, v1 = s1 * inv + sh;
        lds[it * IT + P1O + half * 432 + n * 13 + j] = fmaxf(fmaxf(v0, v1), 0.f);
    }
    __syncthreads();

    // ---- phase 6: conv2 (circular pad 2, K=160) -> h2 (over h1) ----
    // wave -> oc 8w..8w+7; lanes 0..47 = (it, half, ow).
    {
        int wave = tid >> 6, lane = tid & 63;
        int oc0 = __builtin_amdgcn_readfirstlane(wave * 8);
        int l = (lane < 48) ? lane : 0;
        int it = (l >= 24) ? 1 : 0;
        int r = l - it * 24;
        int half = (r >= 12) ? 1 : 0;
        int ow = r - half * 12;
        const float* pbase = &lds[it * IT + P1O + half * 432];
        float* hout = &lds[it * IT + H1O + half * 432];
        int jj[5];
#pragma unroll
        for (int kw = 0; kw < 5; ++kw) {
            int p = ow + kw - 2;
            if (p < 0) p += 12;
            if (p >= 12) p -= 12;
            jj[kw] = p;
        }
        float acc[8];
#pragma unroll
        for (int o = 0; o < 8; ++o) acc[o] = 0.f;
        for (int ic = 0; ic < 32; ++ic) {
            const float* pp = pbase + ic * 13;
            const float* wp = w2 + oc0 * 160 + ic * 5;
#pragma unroll
            for (int kw = 0; kw < 5; ++kw) {
                float pv = pp[jj[kw]];
#pragma unroll
                for (int o = 0; o < 8; ++o) acc[o] += pv * wp[o * 160 + kw];
            }
        }
        if (lane < 48) {
#pragma unroll
            for (int o = 0; o < 8; ++o)
                hout[(oc0 + o) * 13 + ow] = acc[o] + b2[oc0 + o];
        }
    }
    __syncthreads();

    // ---- phase 7: layer-2 scores (n-side own half conv, m-side other half) ----
    {
        int n = tid & 31, grp = tid >> 5;
        int it = grp >> 2, mq = grp & 3;
        const float* H = &lds[it * IT + H1O];  // h2: [half*432 + oc*13 + ow]
        float* A = &lds[it * IT];
#pragma unroll
        for (int half = 0; half < 2; ++half) {
            float pn[12];
            const float* bp = &H[half * 432 + n * 13];
#pragma unroll
            for (int f = 0; f < 12; ++f) pn[f] = bp[f];
#pragma unroll
            for (int i = 0; i < 8; ++i) {
                int m = mq * 8 + i;
                const float* pm = &H[(1 - half) * 432 + m * 13];
                float s = 0.f;
#pragma unroll
                for (int f = 0; f < 12; ++f) s += pn[f] * pm[f];
                s = (s > 0.f) ? s : ALPHA * s;
                A[(half * 32 + m) * 33 + n] = s;
            }
        }
    }
    __syncthreads();

    // ---- phase 8: softmax ----
    {
        int row = tid >> 1, q = tid & 1;
        int it = row >> 6, rm = row & 63;
        float* rp = &lds[it * IT + rm * 33];
        float ev[16];
        float mx = -INFINITY;
#pragma unroll
        for (int k = 0; k < 16; ++k) { ev[k] = rp[q + 2 * k]; mx = fmaxf(mx, ev[k]); }
        mx = fmaxf(mx, __shfl_xor(mx, 1));
        float s = 0.f;
#pragma unroll
        for (int k = 0; k < 16; ++k) { ev[k] = __expf(ev[k] - mx); s += ev[k]; }
        s += __shfl_xor(s, 1);
        float inv = 1.f / s;
#pragma unroll
        for (int k = 0; k < 16; ++k) rp[q + 2 * k] = ev[k] * inv;
    }
    __syncthreads();

    // ---- phase 9+10: (att2 @ h2) -> bn2 -> pool -> relu -> p2f (over p1) ----
    for (int e = tid; e < 768; e += 256) {
        int it = (e >= 384) ? 1 : 0;
        int r = e - it * 384;
        int n = r / 12; int rem = r - n * 12;
        int half = (rem >= 6) ? 1 : 0;
        int j = rem - half * 6;
        const float* A  = &lds[it * IT + half * 1056 + n];
        const float* hv = &lds[it * IT + H1O + half * 432 + 2 * j];
        float s0 = 0.f, s1 = 0.f;
#pragma unroll
        for (int m = 0; m < 32; ++m) {
            float a = A[m * 33];
            s0 += a * hv[m * 13];
            s1 += a * hv[m * 13 + 1];
        }
        float inv = cst[64 + n], sh = cst[96 + n];
        lds[it * IT + P1O + r] = fmaxf(fmaxf(s0 * inv + sh, s1 * inv + sh), 0.f);
    }
    __syncthreads();

    // ---- phase 11: linear 384 -> 13, both items; float4 dot ----
    if (tid < 208) {
        int s8 = tid & 7;
        int rest = tid >> 3;             // 0..25
        int it = (rest >= 13) ? 1 : 0;
        int o = rest - it * 13;
        const float4* wv4 = (const float4*)(lw + o * 384 + s8 * 48);
        const float4* fv4 = (const float4*)&lds[it * IT + P1O + s8 * 48];
        float s = 0.f;
#pragma unroll
        for (int i = 0; i < 12; ++i) {
            float4 w4 = wv4[i];
            float4 f4 = fv4[i];
            s += f4.x * w4.x + f4.y * w4.y + f4.z * w4.z + f4.w * w4.w;
        }
        s += __shfl_down(s, 4, 8);
        s += __shfl_down(s, 2, 8);
        s += __shfl_down(s, 1, 8);
        if (s8 == 0) out[(size_t)(b0 + it) * 13 + o] = s + lb[o];
    }
}

extern "C" void kernel_launch(void* const* d_in, const int* in_sizes, int n_in,
                              void* d_out, int out_size, void* d_ws, size_t ws_size,
                              hipStream_t stream) {
    const float* x   = (const float*)d_in[0];
    const float* w1  = (const float*)d_in[1];
    const float* b1  = (const float*)d_in[2];
    const float* g1  = (const float*)d_in[3];
    const float* be1 = (const float*)d_in[4];
    const float* mu1 = (const float*)d_in[5];
    const float* va1 = (const float*)d_in[6];
    const float* w2  = (const float*)d_in[7];
    const float* b2  = (const float*)d_in[8];
    const float* g2  = (const float*)d_in[9];
    const float* be2 = (const float*)d_in[10];
    const float* mu2 = (const float*)d_in[11];
    const float* va2 = (const float*)d_in[12];
    const float* lw  = (const float*)d_in[13];
    const float* lb  = (const float*)d_in[14];
    float* out = (float*)d_out;

    int B = in_sizes[0] / 1250;  // 16384
    gcn_kernel<<<B / 2, 256, 0, stream>>>(x, w1, b1, g1, be1, mu1, va1,
                                          w2, b2, g2, be2, mu2, va2, lw, lb, out);
}

// Round 6
// 597.472 us; speedup vs baseline: 1.8537x; 1.4346x over previous
//
#include <hip/hip_runtime.h>
#include <math.h>

#define ALPHA 0.2f
#define BN_EPS 1e-5f

typedef __attribute__((ext_vector_type(8))) short short8;
typedef __attribute__((ext_vector_type(4))) float v4f;

// ---- bf16 bit helpers (RNE) ----
__device__ __forceinline__ unsigned short f2bf_rne(float f) {
    union { float f; unsigned u; } x; x.f = f;
    unsigned r = x.u + 0x7FFFu + ((x.u >> 16) & 1u);
    return (unsigned short)(r >> 16);
}
__device__ __forceinline__ float bf2f(unsigned short h) {
    union { float f; unsigned u; } x; x.u = ((unsigned)h) << 16;
    return x.f;
}

// ======== prep kernel: pack conv1 weights as MFMA B-fragments (hi/lo bf16) ========
// K-order: k' = ickh*16 + kw (kw 0..15, pad>=11 zero; ickh 0..25, pad 25 zero).
// Kt = k'/32 in [0,13). Fragment slot s = (Nt*13+Kt)*64+lane holds 8 ushorts:
// element j <-> B[k'=Kt*32+(lane>>4)*8+j][oc=Nt*16+(lane&15)].
// hi at ws16[0..13312), lo at ws16[13312..26624).
__global__ __launch_bounds__(256) void prep_kernel(const float* __restrict__ w1,
                                                   unsigned short* __restrict__ ws16) {
    int s = blockIdx.x * 256 + threadIdx.x;
    if (s >= 1664) return;
    int lane = s & 63;
    int ktnt = s >> 6;           // 0..25
    int Kt = ktnt % 13;
    int Nt = ktnt / 13;
    int oc = Nt * 16 + (lane & 15);
    int quad = lane >> 4;
    for (int j = 0; j < 8; ++j) {
        int kp = Kt * 32 + quad * 8 + j;
        int kw = kp & 15, ickh = kp >> 4;
        float w = 0.f;
        if (kw < 11 && ickh < 25) w = w1[oc * 275 + ickh * 11 + kw];
        unsigned short h = f2bf_rne(w);
        ws16[s * 8 + j] = h;
        ws16[13312 + s * 8 + j] = f2bf_rne(w - bf2f(h));
    }
}

// ======== main kernel ========
// LDS (floats): per-item stride IT=4648 (%32==8):
//   [0,2112)    : xh [2][5][5][25]=1250 (ph 0-1), then aT [2][32][33] (ph 2+)
//   [2112,3776) : h1 [2][32][26] (h2 [half*432+oc*13+ow] aliases, ph 6+)
//   [3776,4640) : p1 [half*432+ic*13+j] (p2f[384] aliases ph 9+)
// cst @9296 [4][32]; abf @9424: conv1 A-panels, 3644 dwords:
//   region R=(it*2+half)*25+ickh (100 regions x 72 bf16 = 36 dwords):
//   copy0[q]=bf16(x(pos=q-5 circ)) q in [0,36); copy1[q]=copy0 shifted +1.
//   dwords [3600,3644) zero slack (padded-K reads land here; must not be NaN).
#define IT 4648
#define H1O 2112
#define P1O 3776
#define CSTO 9296
#define ABFO 9424
#define LDS_TOTAL (9424 + 3644)

__global__ __launch_bounds__(256) void gcn_kernel(
    const float* __restrict__ x,
    const float* __restrict__ w1, const float* __restrict__ b1,
    const float* __restrict__ g1, const float* __restrict__ be1,
    const float* __restrict__ mu1, const float* __restrict__ va1,
    const float* __restrict__ w2, const float* __restrict__ b2,
    const float* __restrict__ g2, const float* __restrict__ be2,
    const float* __restrict__ mu2, const float* __restrict__ va2,
    const float* __restrict__ lw, const float* __restrict__ lb,
    const unsigned short* __restrict__ ws16,
    float* __restrict__ out)
{
    __shared__ float lds[LDS_TOTAL];
    float* cst = lds + CSTO;

    const int tid = threadIdx.x;
    const int b0  = blockIdx.x * 2;

    // ---- phase 0: load 2 items as float2, remap into xh; BN consts ----
    {
        const float2* xg2 = (const float2*)(x + (size_t)b0 * 1250);
        for (int i2 = tid; i2 < 1250; i2 += 256) {
            float2 v = xg2[i2];
            int i = 2 * i2;
            int it = (i >= 1250) ? 1 : 0;
            int j = i - it * 1250;
            int c = j / 250; int r = j - c * 250;
            int h = r / 50;  int w50 = r - h * 50;
            int ha = (w50 >= 25) ? 1 : 0;
            lds[it * IT + ((ha * 5 + c) * 5 + h) * 25 + (w50 - ha * 25)] = v.x;
            int w51 = w50 + 1;
            int hb = (w51 >= 25) ? 1 : 0;
            lds[it * IT + ((hb * 5 + c) * 5 + h) * 25 + (w51 - hb * 25)] = v.y;
        }
    }
    if (tid < 64) {
        int oc = tid & 31;
        if (tid < 32) {
            float inv = g1[oc] * rsqrtf(va1[oc] + BN_EPS);
            cst[oc]      = inv;
            cst[32 + oc] = be1[oc] - mu1[oc] * inv;
        } else {
            float inv = g2[oc] * rsqrtf(va2[oc] + BN_EPS);
            cst[64 + oc] = inv;
            cst[96 + oc] = be2[oc] - mu2[oc] * inv;
        }
    }
    __syncthreads();

    // ---- phase 0.5: stage bf16-RNE A panels (2 parity copies + halo) ----
    {
        unsigned* abf = (unsigned*)(lds + ABFO);
        for (int d = tid; d < 3644; d += 256) {
            unsigned u = 0;
            if (d < 3600) {
                int R = d / 36, o = d - R * 36;
                int cp = (o >= 18) ? 1 : 0;
                int it = R / 50; int R2 = R - it * 50;
                int half = (R2 >= 25) ? 1 : 0;
                int ickh = R2 - half * 25;
                int e = 2 * o - (cp ? 37 : 0);
                const float* src = &lds[it * IT + (half * 25 + ickh) * 25];
                int p0 = e + 20; if (p0 >= 25) p0 -= 25; if (p0 >= 25) p0 -= 25;
                int p1 = e + 21; if (p1 >= 25) p1 -= 25; if (p1 >= 25) p1 -= 25;
                u = (unsigned)f2bf_rne(src[p0]) | ((unsigned)f2bf_rne(src[p1]) << 16);
            }
            abf[d] = u;
        }
    }
    __syncthreads();

    // ---- phase 1: conv1 via MFMA 16x16x32 bf16 (A bf16-RNE, B=hi+lo) ----
    // wave -> (item = w>>1, M-tile pair = (w&1)*2); M rows: m=half*25+pos (<50).
    {
        const int wave = tid >> 6, lane = tid & 63;
        const int it = wave >> 1;
        const int Mtb = (wave & 1) * 2;
        const int quad = lane >> 4, m16 = lane & 15;
        const int kw0 = (quad & 1) * 8;
        const int ickh0 = quad >> 1;
        const unsigned* abf = (const unsigned*)(lds + ABFO);

        int dwb[2];
#pragma unroll
        for (int mt = 0; mt < 2; ++mt) {
            int mg = (Mtb + mt) * 16 + m16;
            int half = (mg >= 25) ? 1 : 0;
            int pos = mg - half * 25; pos = (pos > 24) ? 24 : pos;  // pad rows clamp
            int e0 = pos + kw0;
            int c = e0 & 1;
            int Rb = (it * 2 + half) * 25 + ickh0;
            dwb[mt] = Rb * 36 + c * 18 + ((e0 + c) >> 1);
        }

        v4f zz = {0.f, 0.f, 0.f, 0.f};
        v4f acc[2][2];
        acc[0][0] = zz; acc[0][1] = zz; acc[1][0] = zz; acc[1][1] = zz;

        for (int Kt = 0; Kt < 13; ++Kt) {
            union { unsigned u[4]; short8 v; } af[2];
#pragma unroll
            for (int mt = 0; mt < 2; ++mt) {
                int base = dwb[mt] + Kt * 72;   // R advances by 2 per Kt
                af[mt].u[0] = abf[base + 0];
                af[mt].u[1] = abf[base + 1];
                af[mt].u[2] = abf[base + 2];
                af[mt].u[3] = abf[base + 3];
            }
#pragma unroll
            for (int nt = 0; nt < 2; ++nt) {
                const short8* ph = (const short8*)(ws16 + ((nt * 13 + Kt) * 64 + lane) * 8);
                const short8* pl = (const short8*)(ws16 + 13312 + ((nt * 13 + Kt) * 64 + lane) * 8);
                short8 bh = *ph;
                short8 bl = *pl;
#pragma unroll
                for (int mt = 0; mt < 2; ++mt) {
                    acc[mt][nt] = __builtin_amdgcn_mfma_f32_16x16x32_bf16(af[mt].v, bh, acc[mt][nt], 0, 0, 0);
                    acc[mt][nt] = __builtin_amdgcn_mfma_f32_16x16x32_bf16(af[mt].v, bl, acc[mt][nt], 0, 0, 0);
                }
            }
        }

        // epilogue: D col=lane&15 (oc within tile), row=quad*4+r; add bias, store h1
        float bias0 = b1[m16], bias1 = b1[16 + m16];
        float* hdst = &lds[it * IT + H1O];
#pragma unroll
        for (int mt = 0; mt < 2; ++mt) {
#pragma unroll
            for (int r = 0; r < 4; ++r) {
                int mg = (Mtb + mt) * 16 + quad * 4 + r;
                if (mg < 50) {
                    int half = (mg >= 25) ? 1 : 0;
                    int pos = mg - half * 25;
                    hdst[(half * 32 + m16) * 26 + pos]      = acc[mt][0][r] + bias0;
                    hdst[(half * 32 + 16 + m16) * 26 + pos] = acc[mt][1][r] + bias1;
                }
            }
        }
    }
    __syncthreads();

    // ---- phase 2: scores a[n][m]=<h1[n],h1[m]>, leaky -> aT[m][n] (over xh) ----
    {
        int n = tid & 31, grp = tid >> 5;
        int it = grp >> 2, mq = grp & 3;
        const float* H = &lds[it * IT + H1O];
        float* A = &lds[it * IT];
#pragma unroll
        for (int half = 0; half < 2; ++half) {
            float pn[25];
            const float* bp = &H[(half * 32 + n) * 26];
            const float2* bp2 = (const float2*)bp;
#pragma unroll
            for (int f2 = 0; f2 < 12; ++f2) {
                float2 v = bp2[f2];
                pn[2 * f2] = v.x; pn[2 * f2 + 1] = v.y;
            }
            pn[24] = bp[24];
#pragma unroll
            for (int i = 0; i < 8; ++i) {
                int m = mq * 8 + i;
                const float* pm = &H[(half * 32 + m) * 26];
                const float2* pm2 = (const float2*)pm;
                float s = 0.f;
#pragma unroll
                for (int f2 = 0; f2 < 12; ++f2) {
                    float2 v = pm2[f2];
                    s += pn[2 * f2] * v.x + pn[2 * f2 + 1] * v.y;
                }
                s += pn[24] * pm[24];
                s = (s > 0.f) ? s : ALPHA * s;
                A[(half * 32 + m) * 33 + n] = s;
            }
        }
    }
    __syncthreads();

    // ---- phase 3: softmax over n; 128 rows x 2 lanes ----
    {
        int row = tid >> 1, q = tid & 1;
        int it = row >> 6, rm = row & 63;
        float* rp = &lds[it * IT + rm * 33];
        float ev[16];
        float mx = -INFINITY;
#pragma unroll
        for (int k = 0; k < 16; ++k) { ev[k] = rp[q + 2 * k]; mx = fmaxf(mx, ev[k]); }
        mx = fmaxf(mx, __shfl_xor(mx, 1));
        float s = 0.f;
#pragma unroll
        for (int k = 0; k < 16; ++k) { ev[k] = __expf(ev[k] - mx); s += ev[k]; }
        s += __shfl_xor(s, 1);
        float inv = 1.f / s;
#pragma unroll
        for (int k = 0; k < 16; ++k) rp[q + 2 * k] = ev[k] * inv;
    }
    __syncthreads();

    // ---- phase 4+5: (att @ h1) -> bn1 -> maxpool2 -> relu -> p1 ----
    for (int e = tid; e < 1536; e += 256) {
        int it = (e >= 768) ? 1 : 0;
        int r = e - it * 768;
        int half = (r >= 384) ? 1 : 0;
        int r2 = r - half * 384;
        int n = r2 / 12, j = r2 - n * 12;
        const float* A = &lds[it * IT + half * 1056 + n];
        const float2* hv2 = (const float2*)&lds[it * IT + H1O + half * 832 + 2 * j];
        float s0 = 0.f, s1 = 0.f;
#pragma unroll
        for (int m = 0; m < 32; ++m) {
            float a = A[m * 33];
            float2 v = hv2[m * 13];
            s0 += a * v.x;
            s1 += a * v.y;
        }
        float inv = cst[n], sh = cst[32 + n];
        float v0 = s0 * inv + sh, v1 = s1 * inv + sh;
        lds[it * IT + P1O + half * 432 + n * 13 + j] = fmaxf(fmaxf(v0, v1), 0.f);
    }
    __syncthreads();

    // ---- phase 6: conv2 (circular pad 2, K=160) -> h2 (over h1) ----
    {
        int wave = tid >> 6, lane = tid & 63;
        int oc0 = __builtin_amdgcn_readfirstlane(wave * 8);
        int l = (lane < 48) ? lane : 0;
        int it = (l >= 24) ? 1 : 0;
        int r = l - it * 24;
        int half = (r >= 12) ? 1 : 0;
        int ow = r - half * 12;
        const float* pbase = &lds[it * IT + P1O + half * 432];
        float* hout = &lds[it * IT + H1O + half * 432];
        int jj[5];
#pragma unroll
        for (int kw = 0; kw < 5; ++kw) {
            int p = ow + kw - 2;
            if (p < 0) p += 12;
            if (p >= 12) p -= 12;
            jj[kw] = p;
        }
        float acc[8];
#pragma unroll
        for (int o = 0; o < 8; ++o) acc[o] = 0.f;
        for (int ic = 0; ic < 32; ++ic) {
            const float* pp = pbase + ic * 13;
            const float* wp = w2 + oc0 * 160 + ic * 5;
#pragma unroll
            for (int kw = 0; kw < 5; ++kw) {
                float pv = pp[jj[kw]];
#pragma unroll
                for (int o = 0; o < 8; ++o) acc[o] += pv * wp[o * 160 + kw];
            }
        }
        if (lane < 48) {
#pragma unroll
            for (int o = 0; o < 8; ++o)
                hout[(oc0 + o) * 13 + ow] = acc[o] + b2[oc0 + o];
        }
    }
    __syncthreads();

    // ---- phase 7: layer-2 scores ----
    {
        int n = tid & 31, grp = tid >> 5;
        int it = grp >> 2, mq = grp & 3;
        const float* H = &lds[it * IT + H1O];
        float* A = &lds[it * IT];
#pragma unroll
        for (int half = 0; half < 2; ++half) {
            float pn[12];
            const float* bp = &H[half * 432 + n * 13];
#pragma unroll
            for (int f = 0; f < 12; ++f) pn[f] = bp[f];
#pragma unroll
            for (int i = 0; i < 8; ++i) {
                int m = mq * 8 + i;
                const float* pm = &H[(1 - half) * 432 + m * 13];
                float s = 0.f;
#pragma unroll
                for (int f = 0; f < 12; ++f) s += pn[f] * pm[f];
                s = (s > 0.f) ? s : ALPHA * s;
                A[(half * 32 + m) * 33 + n] = s;
            }
        }
    }
    __syncthreads();

    // ---- phase 8: softmax ----
    {
        int row = tid >> 1, q = tid & 1;
        int it = row >> 6, rm = row & 63;
        float* rp = &lds[it * IT + rm * 33];
        float ev[16];
        float mx = -INFINITY;
#pragma unroll
        for (int k = 0; k < 16; ++k) { ev[k] = rp[q + 2 * k]; mx = fmaxf(mx, ev[k]); }
        mx = fmaxf(mx, __shfl_xor(mx, 1));
        float s = 0.f;
#pragma unroll
        for (int k = 0; k < 16; ++k) { ev[k] = __expf(ev[k] - mx); s += ev[k]; }
        s += __shfl_xor(s, 1);
        float inv = 1.f / s;
#pragma unroll
        for (int k = 0; k < 16; ++k) rp[q + 2 * k] = ev[k] * inv;
    }
    __syncthreads();

    // ---- phase 9+10: (att2 @ h2) -> bn2 -> pool -> relu -> p2f (over p1) ----
    for (int e = tid; e < 768; e += 256) {
        int it = (e >= 384) ? 1 : 0;
        int r = e - it * 384;
        int n = r / 12; int rem = r - n * 12;
        int half = (rem >= 6) ? 1 : 0;
        int j = rem - half * 6;
        const float* A  = &lds[it * IT + half * 1056 + n];
        const float* hv = &lds[it * IT + H1O + half * 432 + 2 * j];
        float s0 = 0.f, s1 = 0.f;
#pragma unroll
        for (int m = 0; m < 32; ++m) {
            float a = A[m * 33];
            s0 += a * hv[m * 13];
            s1 += a * hv[m * 13 + 1];
        }
        float inv = cst[64 + n], sh = cst[96 + n];
        lds[it * IT + P1O + r] = fmaxf(fmaxf(s0 * inv + sh, s1 * inv + sh), 0.f);
    }
    __syncthreads();

    // ---- phase 11: linear 384 -> 13, both items; float4 dot ----
    if (tid < 208) {
        int s8 = tid & 7;
        int rest = tid >> 3;
        int it = (rest >= 13) ? 1 : 0;
        int o = rest - it * 13;
        const float4* wv4 = (const float4*)(lw + o * 384 + s8 * 48);
        const float4* fv4 = (const float4*)&lds[it * IT + P1O + s8 * 48];
        float s = 0.f;
#pragma unroll
        for (int i = 0; i < 12; ++i) {
            float4 w4 = wv4[i];
            float4 f4 = fv4[i];
            s += f4.x * w4.x + f4.y * w4.y + f4.z * w4.z + f4.w * w4.w;
        }
        s += __shfl_down(s, 4, 8);
        s += __shfl_down(s, 2, 8);
        s += __shfl_down(s, 1, 8);
        if (s8 == 0) out[(size_t)(b0 + it) * 13 + o] = s + lb[o];
    }
}

extern "C" void kernel_launch(void* const* d_in, const int* in_sizes, int n_in,
                              void* d_out, int out_size, void* d_ws, size_t ws_size,
                              hipStream_t stream) {
    const float* x   = (const float*)d_in[0];
    const float* w1  = (const float*)d_in[1];
    const float* b1  = (const float*)d_in[2];
    const float* g1  = (const float*)d_in[3];
    const float* be1 = (const float*)d_in[4];
    const float* mu1 = (const float*)d_in[5];
    const float* va1 = (const float*)d_in[6];
    const float* w2  = (const float*)d_in[7];
    const float* b2  = (const float*)d_in[8];
    const float* g2  = (const float*)d_in[9];
    const float* be2 = (const float*)d_in[10];
    const float* mu2 = (const float*)d_in[11];
    const float* va2 = (const float*)d_in[12];
    const float* lw  = (const float*)d_in[13];
    const float* lb  = (const float*)d_in[14];
    float* out = (float*)d_out;
    unsigned short* ws16 = (unsigned short*)d_ws;

    // pack conv1 weights into MFMA B-fragments (hi/lo bf16), 53 KB in d_ws
    prep_kernel<<<7, 256, 0, stream>>>(w1, ws16);

    int B = in_sizes[0] / 1250;  // 16384
    gcn_kernel<<<B / 2, 256, 0, stream>>>(x, w1, b1, g1, be1, mu1, va1,
                                          w2, b2, g2, be2, mu2, va2, lw, lb,
                                          ws16, out);
}